// Round 1
// baseline (212.068 us; speedup 1.0000x reference)
//
#include <hip/hip_runtime.h>
#include <math.h>

#define DD 160
#define HH 160
#define WW 160
#define NB 2
#define NEL (NB*DD*HH*WW)   // 8,192,000 voxels

#define XT 32               // x outputs per block
#define YT 16               // y outputs per block
#define ZC 8                // z outputs per block (v8: split 16->8 for TLP)
#define NTHR 256
#define NZCH (DD/ZC)        // 20
#define GX (WW/XT)          // 5
#define GY (HH/YT)          // 10
#define NBLK (GX*GY*NB*NZCH)   // 2000 blocks x 4 waves = 8000 waves
#define NPART NBLK

#define HR 22               // halo rows (16 + 6)
#define NJOB (HR*8)         // 176 x-conv jobs (< NTHR)
#define CP 35               // c4 physical pitch in float4 (32 + swizzle)

typedef float v2f __attribute__((ext_vector_type(2)));

struct G7 { float g[7]; };

// Fully fused separable 3D SSIM, v8 = v7 + occupancy attack:
//  * ZC 16 -> 8: grid 1000 -> 2000 blocks. v7 was GRID-limited (3.9
//    blocks/CU resident; LDS @25KB allows 6). The per-wave stall
//    (~5400 cy/slice: barrier imbalance + vmcnt waits) is fillable by
//    other blocks' waves; 6 resident blocks/CU make VALU-issue the
//    limiter. Costs +27% slice-iters (z-halo per 8 instead of 16
//    outputs) -- net model ~1.6x.
//  * __launch_bounds__ 4 -> 6 waves/EU (VGPR 52 << 85 budget, no
//    regalloc pressure).
//  * everything else frozen from v7 (reg prefetch, XCD swizzle, v2f
//    pk-fma, c4 swizzle, dbuf, z-rings).
__global__ __launch_bounds__(NTHR, 6) void ssim_fused(
        const float* __restrict__ p, const float* __restrict__ t,
        float* __restrict__ partial, G7 gw) {
    const int tid = threadIdx.x;
    const int tx  = tid & 31;            // x output column (phase C)
    const int tyo = tid >> 5;            // 0..7, owns y = 2tyo, 2tyo+1

    // XCD-aware work remap (bijection on [0,2000), 2000 % 8 == 0)
    const int flat = blockIdx.x;
    const int w = (flat & 7) * (NBLK / 8) + (flat >> 3);
    const int bx = w % GX;
    const int by = (w / GX) % GY;
    const int bz = w / (GX * GY);        // 0..39

    const int x0 = bx * XT;
    const int y0 = by * YT;
    const int n  = bz / NZCH;
    const int zs = (bz % NZCH) * ZC;

    __shared__ float4 c4[2][HR][CP];

    // z rings: [y-out][slot], slot5 freshest
    v2f r01[2][6], r23[2][6];
#pragma unroll
    for (int yo = 0; yo < 2; ++yo)
#pragma unroll
        for (int j = 0; j < 6; ++j) {
            r01[yo][j] = (v2f)(0.f);
            r23[yo][j] = (v2f)(0.f);
        }

    const float C1v = 1e-4f, C2v = 9e-4f;
    float ssum = 0.f;
    const int hw = HH * WW;
    const float* pv = p + (size_t)n * DD * hw;
    const float* tv = t + (size_t)n * DD * hw;

    // phase-B job decode (tid < 176): row br, x-group bxg
    const int br = tid >> 3;             // 0..21
    const int bxg = tid & 7;             // 0..7
    const int bgy = y0 + br - 3;
    const bool browok = (unsigned)bgy < (unsigned)HH && tid < NJOB;
    const int cbase = x0 + 4 * bxg - 4;  // first loaded column (4-aligned)
    const int pcr = tx + (tx >> 3);      // C-phase swizzled column

    float4 pfa[3], pfb[3];
    auto prefetch = [&](int sx) {
#pragma unroll
        for (int q = 0; q < 3; ++q) {
            pfa[q] = make_float4(0.f, 0.f, 0.f, 0.f);
            pfb[q] = make_float4(0.f, 0.f, 0.f, 0.f);
        }
        if (browok && sx >= 0 && sx < DD && sx < zs + ZC + 3) {
            const float* prow = pv + (size_t)sx * hw + bgy * WW;
            const float* trow = tv + (size_t)sx * hw + bgy * WW;
#pragma unroll
            for (int q = 0; q < 3; ++q) {
                int c0 = cbase + 4 * q;
                if ((unsigned)c0 < (unsigned)WW) {
                    pfa[q] = *(const float4*)(prow + c0);
                    pfb[q] = *(const float4*)(trow + c0);
                }
            }
        }
    };

    prefetch(zs - 3);

    for (int s = zs - 3; s < zs + ZC + 3; ++s) {
        const int par = s & 1;
        const bool valid = (s >= 0) && (s < DD);   // block-uniform

        if (valid) {
            // ---- B: x-conv from prefetched registers ----
            if (tid < NJOB) {
                v2f s01[4], s23[4];
#pragma unroll
                for (int e = 0; e < 4; ++e) { s01[e] = (v2f)(0.f); s23[e] = (v2f)(0.f); }
#pragma unroll
                for (int q = 0; q < 3; ++q) {
                    const float af[4] = {pfa[q].x, pfa[q].y, pfa[q].z, pfa[q].w};
                    const float bf[4] = {pfb[q].x, pfb[q].y, pfb[q].z, pfb[q].w};
#pragma unroll
                    for (int j = 0; j < 4; ++j) {
                        const int i = 4 * q + j;     // loaded position 0..11
                        v2f pt; pt[0] = af[j]; pt[1] = bf[j];
                        v2f ud; ud[0] = af[j] + bf[j]; ud[1] = af[j] - bf[j];
                        v2f qu = ud * ud;
#pragma unroll
                        for (int e = 0; e < 4; ++e) {
                            const int k = i - e - 1;  // tap index
                            if (k >= 0 && k < 7) {
                                s01[e] = gw.g[k] * pt + s01[e];
                                s23[e] = gw.g[k] * qu + s23[e];
                            }
                        }
                    }
                }
#pragma unroll
                for (int e = 0; e < 4; ++e) {
                    int c = 4 * bxg + e;
                    c4[par][br][c + (c >> 3)] =
                        make_float4(s01[e][0], s01[e][1], s23[e][0], s23[e][1]);
                }
            }
            __syncthreads();   // block-uniform (valid is uniform)
        }

        // ---- issue next slice's global loads NOW (overlap C + ring) ----
        prefetch(s + 1);

        v2f m01[2], m23[2];
#pragma unroll
        for (int yo = 0; yo < 2; ++yo) {
            m01[yo] = (v2f)(0.f);
            m23[yo] = (v2f)(0.f);
        }

        if (valid) {
            // ---- C: y-conv, stream 8 rows for both y-outputs ----
#pragma unroll
            for (int r8 = 0; r8 < 8; ++r8) {
                float4 v = c4[par][2 * tyo + r8][pcr];
                v2f v01; v01[0] = v.x; v01[1] = v.y;
                v2f v23; v23[0] = v.z; v23[1] = v.w;
                if (r8 < 7) {
                    float w2 = gw.g[r8];
                    m01[0] = w2 * v01 + m01[0];
                    m23[0] = w2 * v23 + m23[0];
                }
                if (r8 > 0) {
                    float w2 = gw.g[r8 - 1];
                    m01[1] = w2 * v01 + m01[1];
                    m23[1] = w2 * v23 + m23[1];
                }
            }
            // no trailing barrier: dbuf; WAR fenced by next slice's barrier.
        }

        // ---- z rings: consume slot0, shift+FMA, refill ----
#pragma unroll
        for (int yo = 0; yo < 2; ++yo) {
            v2f v01 = m01[yo], v23 = m23[yo];
            v2f cons01 = gw.g[6] * v01 + r01[yo][0];
            v2f cons23 = gw.g[6] * v23 + r23[yo][0];
#pragma unroll
            for (int j = 0; j < 5; ++j) {
                r01[yo][j] = gw.g[5 - j] * v01 + r01[yo][j + 1];
                r23[yo][j] = gw.g[5 - j] * v23 + r23[yo][j + 1];
            }
            r01[yo][5] = gw.g[0] * v01;
            r23[yo][5] = gw.g[0] * v23;

            if (s >= zs + 3) {   // output z = s-3
                float mu1 = cons01[0], mu2 = cons01[1];
                float Eu  = cons23[0], Ew  = cons23[1];
                float mu12 = mu1 * mu2, mu1sq = mu1 * mu1, mu2sq = mu2 * mu2;
                float sumsq = 0.5f  * (Eu + Ew) - mu1sq - mu2sq; // s1+s2
                float s12   = 0.25f * (Eu - Ew) - mu12;          // sigma12
                float num = (2.f * mu12 + C1v) * (2.f * s12 + C2v);
                float den = (mu1sq + mu2sq + C1v) * (sumsq + C2v);
                ssum += num * __builtin_amdgcn_rcpf(den);
            }
        }
    }

    // ---- block reduction (4 waves) ----
#pragma unroll
    for (int off = 32; off > 0; off >>= 1)
        ssum += __shfl_down(ssum, off, 64);
    __shared__ float wsum[4];
    if ((tid & 63) == 0) wsum[tid >> 6] = ssum;
    __syncthreads();
    if (tid == 0)
        partial[flat] = wsum[0] + wsum[1] + wsum[2] + wsum[3];
}

__global__ __launch_bounds__(256) void ssim_final(
        const float* __restrict__ partial, float* __restrict__ out) {
    float s = 0.f;
    for (int i = threadIdx.x; i < NPART; i += 256) s += partial[i];
#pragma unroll
    for (int off = 32; off > 0; off >>= 1)
        s += __shfl_down(s, off, 64);
    __shared__ float wsum[4];
    int lane = threadIdx.x & 63, wid = threadIdx.x >> 6;
    if (lane == 0) wsum[wid] = s;
    __syncthreads();
    if (threadIdx.x == 0) {
        float tot = wsum[0] + wsum[1] + wsum[2] + wsum[3];
        out[0] = 1.0f - tot / (float)NEL;
    }
}

extern "C" void kernel_launch(void* const* d_in, const int* in_sizes, int n_in,
                              void* d_out, int out_size, void* d_ws, size_t ws_size,
                              hipStream_t stream) {
    const float* p = (const float*)d_in[0];
    const float* t = (const float*)d_in[1];
    float* out = (float*)d_out;
    float* partial = (float*)d_ws;   // NPART floats

    G7 gw;
    {
        double s = 0.0, sig = 7.0 / 6.0;
        double g[7];
        for (int i = 0; i < 7; ++i) {
            double d = (double)i - 3.0;
            g[i] = exp(-d * d / (2.0 * sig * sig));
            s += g[i];
        }
        for (int i = 0; i < 7; ++i) gw.g[i] = (float)(g[i] / s);
    }

    ssim_fused<<<NBLK, NTHR, 0, stream>>>(p, t, partial, gw);
    ssim_final<<<1, 256, 0, stream>>>(partial, out);
}

// Round 2
// 144.730 us; speedup vs baseline: 1.4653x; 1.4653x over previous
//
#include <hip/hip_runtime.h>
#include <math.h>

#define DD 160
#define HH 160
#define WW 160
#define NB 2
#define NEL (NB*DD*HH*WW)   // 8,192,000 voxels

#define XT 32               // x outputs per block
#define YT 16               // y outputs per block
#define ZC 8                // z outputs per block (v8: split 16->8 for TLP)
#define NTHR 256
#define NZCH (DD/ZC)        // 20
#define GX (WW/XT)          // 5
#define GY (HH/YT)          // 10
#define NBLK (GX*GY*NB*NZCH)   // 2000 blocks x 4 waves = 8000 waves
#define NPART NBLK

#define HR 22               // halo rows (16 + 6)
#define NJOB (HR*8)         // 176 x-conv jobs (< NTHR)
#define CP 35               // c4 physical pitch in float4 (32 + swizzle)

typedef float v2f __attribute__((ext_vector_type(2)));

struct G7 { float g[7]; };

// Fully fused separable 3D SSIM, v9 = v8 with the spill bug fixed:
//  * v8 POST-MORTEM: __launch_bounds__(256,6) capped VGPR 52->40 and the
//    compiler spilled the z-rings/prefetch regs to scratch -- WRITE_SIZE
//    31KB -> 160MB, VALUBusy 48 -> 28, dur 60 -> 140us. The kernel was
//    bound on its own spill traffic.
//  * Residency is LDS-limited anyway: 25KB/block -> 6 blocks/CU with NO
//    register cap needed (6 waves/SIMD x 52 VGPR = 312 < 512). So keep
//    launch_bounds at (256,4) -- cap 128, natural alloc ~52, zero spill --
//    and let the doubled grid (ZC 16->8, 2000 blocks = 7.8/CU available)
//    raise occupancy to the LDS ceiling of 75%.
//  * everything else frozen from v7 (reg prefetch, XCD swizzle, v2f
//    pk-fma, c4 swizzle, dbuf, z-rings).
__global__ __launch_bounds__(NTHR, 4) void ssim_fused(
        const float* __restrict__ p, const float* __restrict__ t,
        float* __restrict__ partial, G7 gw) {
    const int tid = threadIdx.x;
    const int tx  = tid & 31;            // x output column (phase C)
    const int tyo = tid >> 5;            // 0..7, owns y = 2tyo, 2tyo+1

    // XCD-aware work remap (bijection on [0,2000), 2000 % 8 == 0)
    const int flat = blockIdx.x;
    const int w = (flat & 7) * (NBLK / 8) + (flat >> 3);
    const int bx = w % GX;
    const int by = (w / GX) % GY;
    const int bz = w / (GX * GY);        // 0..39

    const int x0 = bx * XT;
    const int y0 = by * YT;
    const int n  = bz / NZCH;
    const int zs = (bz % NZCH) * ZC;

    __shared__ float4 c4[2][HR][CP];

    // z rings: [y-out][slot], slot5 freshest
    v2f r01[2][6], r23[2][6];
#pragma unroll
    for (int yo = 0; yo < 2; ++yo)
#pragma unroll
        for (int j = 0; j < 6; ++j) {
            r01[yo][j] = (v2f)(0.f);
            r23[yo][j] = (v2f)(0.f);
        }

    const float C1v = 1e-4f, C2v = 9e-4f;
    float ssum = 0.f;
    const int hw = HH * WW;
    const float* pv = p + (size_t)n * DD * hw;
    const float* tv = t + (size_t)n * DD * hw;

    // phase-B job decode (tid < 176): row br, x-group bxg
    const int br = tid >> 3;             // 0..21
    const int bxg = tid & 7;             // 0..7
    const int bgy = y0 + br - 3;
    const bool browok = (unsigned)bgy < (unsigned)HH && tid < NJOB;
    const int cbase = x0 + 4 * bxg - 4;  // first loaded column (4-aligned)
    const int pcr = tx + (tx >> 3);      // C-phase swizzled column

    float4 pfa[3], pfb[3];
    auto prefetch = [&](int sx) {
#pragma unroll
        for (int q = 0; q < 3; ++q) {
            pfa[q] = make_float4(0.f, 0.f, 0.f, 0.f);
            pfb[q] = make_float4(0.f, 0.f, 0.f, 0.f);
        }
        if (browok && sx >= 0 && sx < DD && sx < zs + ZC + 3) {
            const float* prow = pv + (size_t)sx * hw + bgy * WW;
            const float* trow = tv + (size_t)sx * hw + bgy * WW;
#pragma unroll
            for (int q = 0; q < 3; ++q) {
                int c0 = cbase + 4 * q;
                if ((unsigned)c0 < (unsigned)WW) {
                    pfa[q] = *(const float4*)(prow + c0);
                    pfb[q] = *(const float4*)(trow + c0);
                }
            }
        }
    };

    prefetch(zs - 3);

    for (int s = zs - 3; s < zs + ZC + 3; ++s) {
        const int par = s & 1;
        const bool valid = (s >= 0) && (s < DD);   // block-uniform

        if (valid) {
            // ---- B: x-conv from prefetched registers ----
            if (tid < NJOB) {
                v2f s01[4], s23[4];
#pragma unroll
                for (int e = 0; e < 4; ++e) { s01[e] = (v2f)(0.f); s23[e] = (v2f)(0.f); }
#pragma unroll
                for (int q = 0; q < 3; ++q) {
                    const float af[4] = {pfa[q].x, pfa[q].y, pfa[q].z, pfa[q].w};
                    const float bf[4] = {pfb[q].x, pfb[q].y, pfb[q].z, pfb[q].w};
#pragma unroll
                    for (int j = 0; j < 4; ++j) {
                        const int i = 4 * q + j;     // loaded position 0..11
                        v2f pt; pt[0] = af[j]; pt[1] = bf[j];
                        v2f ud; ud[0] = af[j] + bf[j]; ud[1] = af[j] - bf[j];
                        v2f qu = ud * ud;
#pragma unroll
                        for (int e = 0; e < 4; ++e) {
                            const int k = i - e - 1;  // tap index
                            if (k >= 0 && k < 7) {
                                s01[e] = gw.g[k] * pt + s01[e];
                                s23[e] = gw.g[k] * qu + s23[e];
                            }
                        }
                    }
                }
#pragma unroll
                for (int e = 0; e < 4; ++e) {
                    int c = 4 * bxg + e;
                    c4[par][br][c + (c >> 3)] =
                        make_float4(s01[e][0], s01[e][1], s23[e][0], s23[e][1]);
                }
            }
            __syncthreads();   // block-uniform (valid is uniform)
        }

        // ---- issue next slice's global loads NOW (overlap C + ring) ----
        prefetch(s + 1);

        v2f m01[2], m23[2];
#pragma unroll
        for (int yo = 0; yo < 2; ++yo) {
            m01[yo] = (v2f)(0.f);
            m23[yo] = (v2f)(0.f);
        }

        if (valid) {
            // ---- C: y-conv, stream 8 rows for both y-outputs ----
#pragma unroll
            for (int r8 = 0; r8 < 8; ++r8) {
                float4 v = c4[par][2 * tyo + r8][pcr];
                v2f v01; v01[0] = v.x; v01[1] = v.y;
                v2f v23; v23[0] = v.z; v23[1] = v.w;
                if (r8 < 7) {
                    float w2 = gw.g[r8];
                    m01[0] = w2 * v01 + m01[0];
                    m23[0] = w2 * v23 + m23[0];
                }
                if (r8 > 0) {
                    float w2 = gw.g[r8 - 1];
                    m01[1] = w2 * v01 + m01[1];
                    m23[1] = w2 * v23 + m23[1];
                }
            }
            // no trailing barrier: dbuf; WAR fenced by next slice's barrier.
        }

        // ---- z rings: consume slot0, shift+FMA, refill ----
#pragma unroll
        for (int yo = 0; yo < 2; ++yo) {
            v2f v01 = m01[yo], v23 = m23[yo];
            v2f cons01 = gw.g[6] * v01 + r01[yo][0];
            v2f cons23 = gw.g[6] * v23 + r23[yo][0];
#pragma unroll
            for (int j = 0; j < 5; ++j) {
                r01[yo][j] = gw.g[5 - j] * v01 + r01[yo][j + 1];
                r23[yo][j] = gw.g[5 - j] * v23 + r23[yo][j + 1];
            }
            r01[yo][5] = gw.g[0] * v01;
            r23[yo][5] = gw.g[0] * v23;

            if (s >= zs + 3) {   // output z = s-3
                float mu1 = cons01[0], mu2 = cons01[1];
                float Eu  = cons23[0], Ew  = cons23[1];
                float mu12 = mu1 * mu2, mu1sq = mu1 * mu1, mu2sq = mu2 * mu2;
                float sumsq = 0.5f  * (Eu + Ew) - mu1sq - mu2sq; // s1+s2
                float s12   = 0.25f * (Eu - Ew) - mu12;          // sigma12
                float num = (2.f * mu12 + C1v) * (2.f * s12 + C2v);
                float den = (mu1sq + mu2sq + C1v) * (sumsq + C2v);
                ssum += num * __builtin_amdgcn_rcpf(den);
            }
        }
    }

    // ---- block reduction (4 waves) ----
#pragma unroll
    for (int off = 32; off > 0; off >>= 1)
        ssum += __shfl_down(ssum, off, 64);
    __shared__ float wsum[4];
    if ((tid & 63) == 0) wsum[tid >> 6] = ssum;
    __syncthreads();
    if (tid == 0)
        partial[flat] = wsum[0] + wsum[1] + wsum[2] + wsum[3];
}

__global__ __launch_bounds__(256) void ssim_final(
        const float* __restrict__ partial, float* __restrict__ out) {
    float s = 0.f;
    for (int i = threadIdx.x; i < NPART; i += 256) s += partial[i];
#pragma unroll
    for (int off = 32; off > 0; off >>= 1)
        s += __shfl_down(s, off, 64);
    __shared__ float wsum[4];
    int lane = threadIdx.x & 63, wid = threadIdx.x >> 6;
    if (lane == 0) wsum[wid] = s;
    __syncthreads();
    if (threadIdx.x == 0) {
        float tot = wsum[0] + wsum[1] + wsum[2] + wsum[3];
        out[0] = 1.0f - tot / (float)NEL;
    }
}

extern "C" void kernel_launch(void* const* d_in, const int* in_sizes, int n_in,
                              void* d_out, int out_size, void* d_ws, size_t ws_size,
                              hipStream_t stream) {
    const float* p = (const float*)d_in[0];
    const float* t = (const float*)d_in[1];
    float* out = (float*)d_out;
    float* partial = (float*)d_ws;   // NPART floats

    G7 gw;
    {
        double s = 0.0, sig = 7.0 / 6.0;
        double g[7];
        for (int i = 0; i < 7; ++i) {
            double d = (double)i - 3.0;
            g[i] = exp(-d * d / (2.0 * sig * sig));
            s += g[i];
        }
        for (int i = 0; i < 7; ++i) gw.g[i] = (float)(g[i] / s);
    }

    ssim_fused<<<NBLK, NTHR, 0, stream>>>(p, t, partial, gw);
    ssim_final<<<1, 256, 0, stream>>>(partial, out);
}

// Round 3
// 128.132 us; speedup vs baseline: 1.6551x; 1.1295x over previous
//
#include <hip/hip_runtime.h>
#include <math.h>

#define DD 160
#define HH 160
#define WW 160
#define NB 2
#define NEL (NB*DD*HH*WW)   // 8,192,000 voxels

#define XT 32               // x outputs per block
#define YT 16               // y outputs per block
#define ZC 16               // z outputs per block (v10: back to v7 -- ZC split bought nothing)
#define NTHR 256
#define NZCH (DD/ZC)        // 10
#define GX (WW/XT)          // 5
#define GY (HH/YT)          // 10
#define NBLK (GX*GY*NB*NZCH)   // 1000 blocks x 4 waves = 4000 waves
#define NPART NBLK

#define HR 22               // halo rows (16 + 6)
#define NJOB (HR*8)         // 176 x-conv jobs (< NTHR)
#define CP 35               // c4 physical pitch in float4 (32 + swizzle)

typedef float v2f __attribute__((ext_vector_type(2)));

struct G7 { float g[7]; };

// Fully fused separable 3D SSIM, v10 = v7 + 2-deep register prefetch.
//  * v8/v9 POST-MORTEM: residency is hard-stuck at ~2.75 blocks/CU for
//    grid=1000 AND grid=2000 (LDS would allow 6) -- occupancy is NOT the
//    lever. Serial time per block-slice S ~ 4400-4700 cy while each wave
//    only issues ~880 cy of VALU -> ~3500 cy/slice of stall. Prime
//    suspect: pf(s+1) is issued after barrier(s) and consumed at B(s+1),
//    a ~700 cy window < L3/HBM latency -> every slice eats a vmcnt stall
//    that the barrier then serializes across all 4 waves.
//  * v10: unroll z-loop by 2 with TWO named prefetch reg sets (pf0 even,
//    pf1 odd -- static indexing, no scratch). Load for slice s+2 issues
//    after barrier(s): cover window = full 2-slice body (~4000 cy).
//    +24 VGPR (~76 total, cap 128 at waves/EU=4 -- no spill).
//  * ZC back to 16: v9's halved chunk added +27% z-halo work for zero
//    occupancy gain.
//  * everything else frozen from v7 (XCD swizzle, v2f pk-fma, c4
//    swizzle, LDS dbuf, z-rings).
__global__ __launch_bounds__(NTHR, 4) void ssim_fused(
        const float* __restrict__ p, const float* __restrict__ t,
        float* __restrict__ partial, G7 gw) {
    const int tid = threadIdx.x;
    const int tx  = tid & 31;            // x output column (phase C)
    const int tyo = tid >> 5;            // 0..7, owns y = 2tyo, 2tyo+1

    // XCD-aware work remap (bijection on [0,1000), 1000 % 8 == 0)
    const int flat = blockIdx.x;
    const int w = (flat & 7) * (NBLK / 8) + (flat >> 3);
    const int bx = w % GX;
    const int by = (w / GX) % GY;
    const int bz = w / (GX * GY);        // 0..19

    const int x0 = bx * XT;
    const int y0 = by * YT;
    const int n  = bz / NZCH;
    const int zs = (bz % NZCH) * ZC;

    __shared__ float4 c4[2][HR][CP];

    // z rings: [y-out][slot], slot5 freshest
    v2f r01[2][6], r23[2][6];
#pragma unroll
    for (int yo = 0; yo < 2; ++yo)
#pragma unroll
        for (int j = 0; j < 6; ++j) {
            r01[yo][j] = (v2f)(0.f);
            r23[yo][j] = (v2f)(0.f);
        }

    const float C1v = 1e-4f, C2v = 9e-4f;
    float ssum = 0.f;
    const int hw = HH * WW;
    const float* pv = p + (size_t)n * DD * hw;
    const float* tv = t + (size_t)n * DD * hw;

    // phase-B job decode (tid < 176): row br, x-group bxg
    const int br = tid >> 3;             // 0..21
    const int bxg = tid & 7;             // 0..7
    const int bgy = y0 + br - 3;
    const bool browok = (unsigned)bgy < (unsigned)HH && tid < NJOB;
    const int cbase = x0 + 4 * bxg - 4;  // first loaded column (4-aligned)
    const int pcr = tx + (tx >> 3);      // C-phase swizzled column

    // two independent prefetch register sets (even/odd slice)
    float4 pfa0[3], pfb0[3], pfa1[3], pfb1[3];

    auto prefetch = [&](int sx, float4 (&A)[3], float4 (&B)[3]) {
#pragma unroll
        for (int q = 0; q < 3; ++q) {
            A[q] = make_float4(0.f, 0.f, 0.f, 0.f);
            B[q] = make_float4(0.f, 0.f, 0.f, 0.f);
        }
        if (browok && sx >= 0 && sx < DD && sx < zs + ZC + 3) {
            const float* prow = pv + (size_t)sx * hw + bgy * WW;
            const float* trow = tv + (size_t)sx * hw + bgy * WW;
#pragma unroll
            for (int q = 0; q < 3; ++q) {
                int c0 = cbase + 4 * q;
                if ((unsigned)c0 < (unsigned)WW) {
                    A[q] = *(const float4*)(prow + c0);
                    B[q] = *(const float4*)(trow + c0);
                }
            }
        }
    };

    // one z-slice body; Pa/Pb hold slice s's row data; pf_s is the slice
    // whose loads we issue into the SAME regs right after the barrier
    // (consumed 2 slices later -> full 2-slice latency cover window).
    auto slice = [&](int s, float4 (&Pa)[3], float4 (&Pb)[3], int pf_s) {
        const int par = s & 1;
        const bool valid = (s >= 0) && (s < DD);   // block-uniform

        if (valid) {
            // ---- B: x-conv from prefetched registers ----
            if (tid < NJOB) {
                v2f s01[4], s23[4];
#pragma unroll
                for (int e = 0; e < 4; ++e) { s01[e] = (v2f)(0.f); s23[e] = (v2f)(0.f); }
#pragma unroll
                for (int q = 0; q < 3; ++q) {
                    const float af[4] = {Pa[q].x, Pa[q].y, Pa[q].z, Pa[q].w};
                    const float bf[4] = {Pb[q].x, Pb[q].y, Pb[q].z, Pb[q].w};
#pragma unroll
                    for (int j = 0; j < 4; ++j) {
                        const int i = 4 * q + j;     // loaded position 0..11
                        v2f pt; pt[0] = af[j]; pt[1] = bf[j];
                        v2f ud; ud[0] = af[j] + bf[j]; ud[1] = af[j] - bf[j];
                        v2f qu = ud * ud;
#pragma unroll
                        for (int e = 0; e < 4; ++e) {
                            const int k = i - e - 1;  // tap index
                            if (k >= 0 && k < 7) {
                                s01[e] = gw.g[k] * pt + s01[e];
                                s23[e] = gw.g[k] * qu + s23[e];
                            }
                        }
                    }
                }
#pragma unroll
                for (int e = 0; e < 4; ++e) {
                    int c = 4 * bxg + e;
                    c4[par][br][c + (c >> 3)] =
                        make_float4(s01[e][0], s01[e][1], s23[e][0], s23[e][1]);
                }
            }
            __syncthreads();   // block-uniform (valid is uniform)
        }

        // ---- issue slice pf_s's global loads NOW (2-slice cover window) ----
        prefetch(pf_s, Pa, Pb);

        v2f m01[2], m23[2];
#pragma unroll
        for (int yo = 0; yo < 2; ++yo) {
            m01[yo] = (v2f)(0.f);
            m23[yo] = (v2f)(0.f);
        }

        if (valid) {
            // ---- C: y-conv, stream 8 rows for both y-outputs ----
#pragma unroll
            for (int r8 = 0; r8 < 8; ++r8) {
                float4 v = c4[par][2 * tyo + r8][pcr];
                v2f v01; v01[0] = v.x; v01[1] = v.y;
                v2f v23; v23[0] = v.z; v23[1] = v.w;
                if (r8 < 7) {
                    float w2 = gw.g[r8];
                    m01[0] = w2 * v01 + m01[0];
                    m23[0] = w2 * v23 + m23[0];
                }
                if (r8 > 0) {
                    float w2 = gw.g[r8 - 1];
                    m01[1] = w2 * v01 + m01[1];
                    m23[1] = w2 * v23 + m23[1];
                }
            }
            // no trailing barrier: dbuf; WAR fenced by next slice's barrier.
        }

        // ---- z rings: consume slot0, shift+FMA, refill ----
#pragma unroll
        for (int yo = 0; yo < 2; ++yo) {
            v2f v01 = m01[yo], v23 = m23[yo];
            v2f cons01 = gw.g[6] * v01 + r01[yo][0];
            v2f cons23 = gw.g[6] * v23 + r23[yo][0];
#pragma unroll
            for (int j = 0; j < 5; ++j) {
                r01[yo][j] = gw.g[5 - j] * v01 + r01[yo][j + 1];
                r23[yo][j] = gw.g[5 - j] * v23 + r23[yo][j + 1];
            }
            r01[yo][5] = gw.g[0] * v01;
            r23[yo][5] = gw.g[0] * v23;

            if (s >= zs + 3) {   // output z = s-3
                float mu1 = cons01[0], mu2 = cons01[1];
                float Eu  = cons23[0], Ew  = cons23[1];
                float mu12 = mu1 * mu2, mu1sq = mu1 * mu1, mu2sq = mu2 * mu2;
                float sumsq = 0.5f  * (Eu + Ew) - mu1sq - mu2sq; // s1+s2
                float s12   = 0.25f * (Eu - Ew) - mu12;          // sigma12
                float num = (2.f * mu12 + C1v) * (2.f * s12 + C2v);
                float den = (mu1sq + mu2sq + C1v) * (sumsq + C2v);
                ssum += num * __builtin_amdgcn_rcpf(den);
            }
        }
    };

    // prologue: fill both prefetch sets (slices zs-3, zs-2)
    prefetch(zs - 3, pfa0, pfb0);
    prefetch(zs - 2, pfa1, pfb1);

    // 22 slices = 11 double-iterations (ZC+6 is even)
    for (int s = zs - 3; s < zs + ZC + 3; s += 2) {
        slice(s,     pfa0, pfb0, s + 2);
        slice(s + 1, pfa1, pfb1, s + 3);
    }

    // ---- block reduction (4 waves) ----
#pragma unroll
    for (int off = 32; off > 0; off >>= 1)
        ssum += __shfl_down(ssum, off, 64);
    __shared__ float wsum[4];
    if ((tid & 63) == 0) wsum[tid >> 6] = ssum;
    __syncthreads();
    if (tid == 0)
        partial[flat] = wsum[0] + wsum[1] + wsum[2] + wsum[3];
}

__global__ __launch_bounds__(256) void ssim_final(
        const float* __restrict__ partial, float* __restrict__ out) {
    float s = 0.f;
    for (int i = threadIdx.x; i < NPART; i += 256) s += partial[i];
#pragma unroll
    for (int off = 32; off > 0; off >>= 1)
        s += __shfl_down(s, off, 64);
    __shared__ float wsum[4];
    int lane = threadIdx.x & 63, wid = threadIdx.x >> 6;
    if (lane == 0) wsum[wid] = s;
    __syncthreads();
    if (threadIdx.x == 0) {
        float tot = wsum[0] + wsum[1] + wsum[2] + wsum[3];
        out[0] = 1.0f - tot / (float)NEL;
    }
}

extern "C" void kernel_launch(void* const* d_in, const int* in_sizes, int n_in,
                              void* d_out, int out_size, void* d_ws, size_t ws_size,
                              hipStream_t stream) {
    const float* p = (const float*)d_in[0];
    const float* t = (const float*)d_in[1];
    float* out = (float*)d_out;
    float* partial = (float*)d_ws;   // NPART floats

    G7 gw;
    {
        double s = 0.0, sig = 7.0 / 6.0;
        double g[7];
        for (int i = 0; i < 7; ++i) {
            double d = (double)i - 3.0;
            g[i] = exp(-d * d / (2.0 * sig * sig));
            s += g[i];
        }
        for (int i = 0; i < 7; ++i) gw.g[i] = (float)(g[i] / s);
    }

    ssim_fused<<<NBLK, NTHR, 0, stream>>>(p, t, partial, gw);
    ssim_final<<<1, 256, 0, stream>>>(partial, out);
}